// Round 1
// baseline (436.421 us; speedup 1.0000x reference)
//
#include <hip/hip_runtime.h>
#include <math.h>

#define EDIM 768
#define NH 12
#define HD 64
#define BSZ 8
#define NN 512
#define NCAT 1664          // 768(q) + 768(k) + 36(vw) padded to 13*128
#define SCALE 0.125f       // 64^-0.5

// ---------------- K0: init output with channel biases ----------------
__global__ void k_init_out(float* __restrict__ out, const float* b1, const float* b2, const float* b3) {
    int idx = blockIdx.x * 256 + threadIdx.x;
    if (idx < BSZ * NN * 3) {
        int c = idx % 3;
        out[idx] = (c == 0) ? b1[0] : (c == 1) ? b2[0] : b3[0];
    }
}

// ---------------- K1: build concatenated weight Wcat[e][o] ----------------
// o<768: Wq ; o<1536: Wk ; o<1572: Wvc[e][h*3+c] = sum_d Wv[e][h*64+d]*Wc[h*64+d] ; else 0
__global__ void k_build_wcat(float* __restrict__ Wcat,
                             const float* __restrict__ Wq, const float* __restrict__ Wk,
                             const float* __restrict__ Wv,
                             const float* __restrict__ W1, const float* __restrict__ W2,
                             const float* __restrict__ W3) {
    int idx = blockIdx.x * 256 + threadIdx.x;
    if (idx >= EDIM * NCAT) return;
    int e = idx / NCAT, o = idx - (idx / NCAT) * NCAT;
    float v = 0.f;
    if (o < 768) {
        v = Wq[e * EDIM + o];
    } else if (o < 1536) {
        v = Wk[e * EDIM + (o - 768)];
    } else if (o < 1572) {
        int o2 = o - 1536;
        int h = o2 / 3, c = o2 - (o2 / 3) * 3;
        const float* Wc = (c == 0) ? W1 : (c == 1) ? W2 : W3;
        float s = 0.f;
        #pragma unroll 8
        for (int d = 0; d < HD; d++) s += Wv[e * EDIM + h * HD + d] * Wc[h * HD + d];
        v = s;
    }
    Wcat[idx] = v;
}

// ---------------- K1b: concatenated bias ----------------
__global__ void k_build_bcat(float* __restrict__ bcat,
                             const float* __restrict__ bq, const float* __restrict__ bk,
                             const float* __restrict__ bv,
                             const float* __restrict__ W1, const float* __restrict__ W2,
                             const float* __restrict__ W3) {
    int o = blockIdx.x * 256 + threadIdx.x;
    if (o >= NCAT) return;
    float v = 0.f;
    if (o < 768) v = bq[o];
    else if (o < 1536) v = bk[o - 768];
    else if (o < 1572) {
        int o2 = o - 1536;
        int h = o2 / 3, c = o2 - (o2 / 3) * 3;
        const float* Wc = (c == 0) ? W1 : (c == 1) ? W2 : W3;
        float s = 0.f;
        for (int d = 0; d < HD; d++) s += bv[h * HD + d] * Wc[h * HD + d];
        v = s;
    }
    bcat[o] = v;
}

// ---------------- K2: fused projection GEMM  C(4096x1664) = X(4096x768) @ Wcat ----------------
// X[m][e] = query[i][b][e], m = b*512+i.  128x128 tile, K-step 8, 8x8 micro-tile.
// Epilogue scatters into q (scaled), k, vw buffers.
__global__ __launch_bounds__(256) void k_gemm_qkv(
        const float* __restrict__ query, const float* __restrict__ Wcat,
        const float* __restrict__ bcat,
        float* __restrict__ qb, float* __restrict__ kb, float* __restrict__ vwb) {
    __shared__ float As[8][132];   // As[k][m]
    __shared__ float Bs[8][132];   // Bs[k][n]
    const int t = threadIdx.x;
    const int m0 = blockIdx.x * 128;
    const int n0 = blockIdx.y * 128;
    const int tx = t & 15, ty = t >> 4;

    const int ar = t >> 1;          // row 0..127 of A tile
    const int ak = (t & 1) * 4;     // k offset 0 or 4
    const int am = m0 + ar;
    const float* xrow = query + ((size_t)(am & (NN - 1)) * BSZ + (am >> 9)) * EDIM;

    const int be = t >> 5, bg = t & 31;
    const float* bsrc = Wcat + (size_t)be * NCAT + n0 + bg * 4;

    float acc[8][8];
    #pragma unroll
    for (int u = 0; u < 8; u++)
        #pragma unroll
        for (int v = 0; v < 8; v++) acc[u][v] = 0.f;

    for (int k0 = 0; k0 < EDIM; k0 += 8) {
        float4 av = *(const float4*)(xrow + k0 + ak);
        float4 bv = *(const float4*)(bsrc + (size_t)k0 * NCAT);
        __syncthreads();
        As[ak + 0][ar] = av.x; As[ak + 1][ar] = av.y;
        As[ak + 2][ar] = av.z; As[ak + 3][ar] = av.w;
        *(float4*)&Bs[be][bg * 4] = bv;
        __syncthreads();
        #pragma unroll
        for (int kk = 0; kk < 8; kk++) {
            float a[8], b[8];
            *(float4*)(a)     = *(const float4*)&As[kk][ty * 8];
            *(float4*)(a + 4) = *(const float4*)&As[kk][ty * 8 + 4];
            *(float4*)(b)     = *(const float4*)&Bs[kk][tx * 8];
            *(float4*)(b + 4) = *(const float4*)&Bs[kk][tx * 8 + 4];
            #pragma unroll
            for (int u = 0; u < 8; u++)
                #pragma unroll
                for (int v = 0; v < 8; v++) acc[u][v] = fmaf(a[u], b[v], acc[u][v]);
        }
    }

    #pragma unroll
    for (int u = 0; u < 8; u++) {
        int mm = m0 + ty * 8 + u;
        int b_ = mm >> 9, i_ = mm & (NN - 1);
        #pragma unroll
        for (int v = 0; v < 8; v++) {
            int o = n0 + tx * 8 + v;
            float val = acc[u][v] + bcat[o];
            if (o < 768) {
                int h = o >> 6, d = o & 63;
                qb[(((size_t)b_ * NH + h) * NN + i_) * HD + d] = val * SCALE;
            } else if (o < 1536) {
                int o2 = o - 768;
                int h = o2 >> 6, d = o2 & 63;
                kb[(((size_t)b_ * NH + h) * NN + i_) * HD + d] = val;
            } else if (o < 1572) {
                int o2 = o - 1536;
                int h = o2 / 3, c = o2 - (o2 / 3) * 3;
                vwb[(((size_t)b_ * NH + h) * NN + i_) * 3 + c] = val;
            }
        }
    }
}

// ---------------- K4: fused attention + rotational reduce ----------------
// block = (b, h, i-tile of 64). Online softmax; accumulates
// a_c[i] = sum_j exp(s_ij - m) * vw_c[j] * delta_c(i,j); out += a_c / l  (atomic over h)
__global__ __launch_bounds__(256) void k_attn(
        const float* __restrict__ qb, const float* __restrict__ kb,
        const float* __restrict__ vwb, const float* __restrict__ bias,
        const float* __restrict__ pos, float* __restrict__ out) {
    __shared__ float qs[64][68];
    __shared__ float ks[64][68];
    __shared__ float px[NN], py[NN], pz[NN];
    __shared__ float w0[NN], w1[NN], w2[NN];

    const int t = threadIdx.x;
    const int bid = blockIdx.x;
    const int it = bid & 7;
    const int h = (bid >> 3) % NH;
    const int b = bid / (8 * NH);
    const int i0 = it * 64;

    // stage positions + vw for this (b,h)
    for (int idx = t; idx < NN * 3; idx += 256) {
        int j = idx / 3, c = idx - (idx / 3) * 3;
        float pv = pos[(size_t)b * (NN * 3) + idx];
        float wv = vwb[((size_t)b * NH + h) * (NN * 3) + idx];
        if (c == 0) { px[j] = pv; w0[j] = wv; }
        else if (c == 1) { py[j] = pv; w1[j] = wv; }
        else { pz[j] = pv; w2[j] = wv; }
    }
    // stage q tile (64 rows x 64)
    {
        int r = t >> 2, cp = t & 3;
        const float* qrow = qb + (((size_t)b * NH + h) * NN + i0 + r) * HD;
        #pragma unroll
        for (int u = 0; u < 4; u++) {
            int d = cp * 4 + u * 16;
            *(float4*)&qs[r][d] = *(const float4*)(qrow + d);
        }
    }

    const int tx = t & 15, ty = t >> 4;  // thread owns rows ty*4..+3, cols tx*4..+3 per tile
    float m_r[4], l_r[4], a0[4], a1[4], a2[4];
    #pragma unroll
    for (int u = 0; u < 4; u++) { m_r[u] = -3.0e38f; l_r[u] = 0.f; a0[u] = 0.f; a1[u] = 0.f; a2[u] = 0.f; }

    for (int jt = 0; jt < 8; jt++) {
        const int j0 = jt * 64;
        // load k tile into regs, then LDS
        int r = t >> 2, cp = t & 3;
        const float* krow = kb + (((size_t)b * NH + h) * NN + j0 + r) * HD;
        float4 kv[4];
        #pragma unroll
        for (int u = 0; u < 4; u++) kv[u] = *(const float4*)(krow + cp * 4 + u * 16);
        __syncthreads();
        #pragma unroll
        for (int u = 0; u < 4; u++) *(float4*)&ks[r][cp * 4 + u * 16] = kv[u];
        __syncthreads();

        // 64x64 QK^T tile, 4x4 micro
        float acc[4][4];
        #pragma unroll
        for (int ui = 0; ui < 4; ui++)
            #pragma unroll
            for (int uj = 0; uj < 4; uj++) acc[ui][uj] = 0.f;
        for (int d = 0; d < HD; d += 4) {
            float4 q4[4], k4[4];
            #pragma unroll
            for (int u = 0; u < 4; u++) {
                q4[u] = *(const float4*)&qs[ty * 4 + u][d];
                k4[u] = *(const float4*)&ks[tx * 4 + u][d];
            }
            #pragma unroll
            for (int ui = 0; ui < 4; ui++)
                #pragma unroll
                for (int uj = 0; uj < 4; uj++)
                    acc[ui][uj] += q4[ui].x * k4[uj].x + q4[ui].y * k4[uj].y +
                                   q4[ui].z * k4[uj].z + q4[ui].w * k4[uj].w;
        }
        // + bias
        #pragma unroll
        for (int ui = 0; ui < 4; ui++) {
            int ig = i0 + ty * 4 + ui;
            float4 bv = *(const float4*)(bias + (((size_t)b * NH + h) * NN + ig) * NN + j0 + tx * 4);
            acc[ui][0] += bv.x; acc[ui][1] += bv.y; acc[ui][2] += bv.z; acc[ui][3] += bv.w;
        }
        // per-column data
        float w0j[4], w1j[4], w2j[4], pxj[4], pyj[4], pzj[4];
        #pragma unroll
        for (int uj = 0; uj < 4; uj++) {
            int j = j0 + tx * 4 + uj;
            w0j[uj] = w0[j]; w1j[uj] = w1[j]; w2j[uj] = w2[j];
            pxj[uj] = px[j]; pyj[uj] = py[j]; pzj[uj] = pz[j];
        }
        // online softmax + weighted reduce (row groups = 16 lanes sharing ty)
        #pragma unroll
        for (int ui = 0; ui < 4; ui++) {
            int il = i0 + ty * 4 + ui;
            float qx = px[il], qy = py[il], qz = pz[il];
            float tm = fmaxf(fmaxf(acc[ui][0], acc[ui][1]), fmaxf(acc[ui][2], acc[ui][3]));
            #pragma unroll
            for (int off = 1; off < 16; off <<= 1) tm = fmaxf(tm, __shfl_xor(tm, off, 64));
            float mn = fmaxf(m_r[ui], tm);
            float alpha = __expf(m_r[ui] - mn);
            float lp = 0.f, s0 = 0.f, s1 = 0.f, s2 = 0.f;
            #pragma unroll
            for (int uj = 0; uj < 4; uj++) {
                float p = __expf(acc[ui][uj] - mn);
                lp += p;
                float dx = pxj[uj] - qx, dy = pyj[uj] - qy, dz = pzj[uj] - qz;
                float inv = 1.f / (sqrtf(dx * dx + dy * dy + dz * dz) + 1e-5f);
                float pw = p * inv;
                s0 += pw * w0j[uj] * dx;
                s1 += pw * w1j[uj] * dy;
                s2 += pw * w2j[uj] * dz;
            }
            #pragma unroll
            for (int off = 1; off < 16; off <<= 1) {
                lp += __shfl_xor(lp, off, 64);
                s0 += __shfl_xor(s0, off, 64);
                s1 += __shfl_xor(s1, off, 64);
                s2 += __shfl_xor(s2, off, 64);
            }
            l_r[ui] = l_r[ui] * alpha + lp;
            a0[ui] = a0[ui] * alpha + s0;
            a1[ui] = a1[ui] * alpha + s1;
            a2[ui] = a2[ui] * alpha + s2;
            m_r[ui] = mn;
        }
    }

    if (tx == 0) {
        #pragma unroll
        for (int ui = 0; ui < 4; ui++) {
            int ig = i0 + ty * 4 + ui;
            float invl = 1.f / l_r[ui];
            atomicAdd(out + ((size_t)b * NN + ig) * 3 + 0, a0[ui] * invl);
            atomicAdd(out + ((size_t)b * NN + ig) * 3 + 1, a1[ui] * invl);
            atomicAdd(out + ((size_t)b * NN + ig) * 3 + 2, a2[ui] * invl);
        }
    }
}

extern "C" void kernel_launch(void* const* d_in, const int* in_sizes, int n_in,
                              void* d_out, int out_size, void* d_ws, size_t ws_size,
                              hipStream_t stream) {
    const float* query = (const float*)d_in[0];
    const float* bias  = (const float*)d_in[1];
    const float* pos   = (const float*)d_in[2];
    const float* Wq = (const float*)d_in[3];
    const float* bq = (const float*)d_in[4];
    const float* Wk = (const float*)d_in[5];
    const float* bk = (const float*)d_in[6];
    const float* Wv = (const float*)d_in[7];
    const float* bv = (const float*)d_in[8];
    const float* W1 = (const float*)d_in[9];
    const float* b1 = (const float*)d_in[10];
    const float* W2 = (const float*)d_in[11];
    const float* b2 = (const float*)d_in[12];
    const float* W3 = (const float*)d_in[13];
    const float* b3 = (const float*)d_in[14];
    float* out = (float*)d_out;

    float* wsf  = (float*)d_ws;
    float* Wcat = wsf;                                   // 768*1664
    float* bcat = Wcat + (size_t)EDIM * NCAT;            // 1664
    float* qb   = bcat + NCAT;                           // 8*12*512*64
    float* kb   = qb + (size_t)BSZ * NH * NN * HD;       // 8*12*512*64
    float* vwb  = kb + (size_t)BSZ * NH * NN * HD;       // 8*12*512*3

    k_init_out<<<(BSZ * NN * 3 + 255) / 256, 256, 0, stream>>>(out, b1, b2, b3);
    k_build_wcat<<<(EDIM * NCAT + 255) / 256, 256, 0, stream>>>(Wcat, Wq, Wk, Wv, W1, W2, W3);
    k_build_bcat<<<(NCAT + 255) / 256, 256, 0, stream>>>(bcat, bq, bk, bv, W1, W2, W3);
    dim3 g2(32, 13);
    k_gemm_qkv<<<g2, 256, 0, stream>>>(query, Wcat, bcat, qb, kb, vwb);
    k_attn<<<BSZ * NH * 8, 256, 0, stream>>>(qb, kb, vwb, bias, pos, out);
}

// Round 2
// 269.531 us; speedup vs baseline: 1.6192x; 1.6192x over previous
//
#include <hip/hip_runtime.h>
#include <math.h>

#define EDIM 768
#define NH 12
#define HD 64
#define BSZ 8
#define NN 512
#define NCAT 1664          // 768(q) + 768(k) + 36(vw) padded to 13*128

typedef short short8 __attribute__((ext_vector_type(8)));
typedef float f32x4 __attribute__((ext_vector_type(4)));

__device__ __forceinline__ unsigned short f2bf(float x) {
    unsigned int u = __float_as_uint(x);
    u = (u + 0x7FFF + ((u >> 16) & 1)) >> 16;   // RNE
    return (unsigned short)u;
}
__device__ __forceinline__ float bf2f(unsigned short s) {
    return __uint_as_float(((unsigned int)s) << 16);
}
__device__ __forceinline__ void gl2lds16(const void* g, void* l) {
    __builtin_amdgcn_global_load_lds(
        (const __attribute__((address_space(1))) unsigned int*)g,
        (__attribute__((address_space(3))) unsigned int*)l, 16, 0, 0);
}

// ---------------- K0: init output with channel biases ----------------
__global__ void k_init_out(float* __restrict__ out, const float* b1, const float* b2, const float* b3) {
    int idx = blockIdx.x * 256 + threadIdx.x;
    if (idx < BSZ * NN * 3) {
        int c = idx % 3;
        out[idx] = (c == 0) ? b1[0] : (c == 1) ? b2[0] : b3[0];
    }
}

// ---------------- K1: build concatenated weight Wcat[e][o] (fp32) ----------------
__global__ void k_build_wcat(float* __restrict__ Wcat,
                             const float* __restrict__ Wq, const float* __restrict__ Wk,
                             const float* __restrict__ Wv,
                             const float* __restrict__ W1, const float* __restrict__ W2,
                             const float* __restrict__ W3) {
    int idx = blockIdx.x * 256 + threadIdx.x;
    if (idx >= EDIM * NCAT) return;
    int e = idx / NCAT, o = idx - (idx / NCAT) * NCAT;
    float v = 0.f;
    if (o < 768) {
        v = Wq[e * EDIM + o];
    } else if (o < 1536) {
        v = Wk[e * EDIM + (o - 768)];
    } else if (o < 1572) {
        int o2 = o - 1536;
        int h = o2 / 3, c = o2 - (o2 / 3) * 3;
        const float* Wc = (c == 0) ? W1 : (c == 1) ? W2 : W3;
        float s = 0.f;
        #pragma unroll 8
        for (int d = 0; d < HD; d++) s += Wv[e * EDIM + h * HD + d] * Wc[h * HD + d];
        v = s;
    }
    Wcat[idx] = v;
}

// ---------------- K1b: concatenated bias (fp32) ----------------
__global__ void k_build_bcat(float* __restrict__ bcat,
                             const float* __restrict__ bq, const float* __restrict__ bk,
                             const float* __restrict__ bv,
                             const float* __restrict__ W1, const float* __restrict__ W2,
                             const float* __restrict__ W3) {
    int o = blockIdx.x * 256 + threadIdx.x;
    if (o >= NCAT) return;
    float v = 0.f;
    if (o < 768) v = bq[o];
    else if (o < 1536) v = bk[o - 768];
    else if (o < 1572) {
        int o2 = o - 1536;
        int h = o2 / 3, c = o2 - (o2 / 3) * 3;
        const float* Wc = (c == 0) ? W1 : (c == 1) ? W2 : W3;
        float s = 0.f;
        for (int d = 0; d < HD; d++) s += bv[h * HD + d] * Wc[h * HD + d];
        v = s;
    }
    bcat[o] = v;
}

// ---------------- K1c: transpose Wcat -> WT[n][e] bf16 (K-contiguous for MFMA B) ----------------
__global__ __launch_bounds__(256) void k_transpose_wcat(const float* __restrict__ Wcat,
                                                        unsigned short* __restrict__ WT) {
    __shared__ float tile[32][33];
    const int tx = threadIdx.x & 31, ty = threadIdx.x >> 5;
    const int n0 = blockIdx.x * 32, e0 = blockIdx.y * 32;
    #pragma unroll
    for (int s = 0; s < 4; s++)
        tile[ty + s * 8][tx] = Wcat[(size_t)(e0 + ty + s * 8) * NCAT + n0 + tx];
    __syncthreads();
    #pragma unroll
    for (int s = 0; s < 4; s++)
        WT[(size_t)(n0 + ty + s * 8) * EDIM + e0 + tx] = f2bf(tile[tx][ty + s * 8]);
}

// ---------------- K1d: query (n,b,e) fp32 -> Xb[m=b*512+i][e] bf16 ----------------
__global__ __launch_bounds__(256) void k_cvt_x(const float* __restrict__ q, unsigned short* __restrict__ Xb) {
    int idx = blockIdx.x * 256 + threadIdx.x;      // 4096*96
    int m = idx / 96, e8 = (idx - (idx / 96) * 96) * 8;
    int b = m >> 9, i = m & (NN - 1);
    const float* src = q + ((size_t)i * BSZ + b) * EDIM + e8;
    float4 v0 = *(const float4*)src;
    float4 v1 = *(const float4*)(src + 4);
    unsigned int p0 = f2bf(v0.x) | ((unsigned int)f2bf(v0.y) << 16);
    unsigned int p1 = f2bf(v0.z) | ((unsigned int)f2bf(v0.w) << 16);
    unsigned int p2 = f2bf(v1.x) | ((unsigned int)f2bf(v1.y) << 16);
    unsigned int p3 = f2bf(v1.z) | ((unsigned int)f2bf(v1.w) << 16);
    uint4 pk = {p0, p1, p2, p3};
    *(uint4*)&Xb[(size_t)idx * 8] = pk;
}

// ---------------- K1e: geometry precompute ud_c[b][i][j] = delta_c/(dist+eps), bf16 ----------------
__global__ __launch_bounds__(256) void k_geom(const float* __restrict__ pos,
                                              unsigned short* __restrict__ ud0,
                                              unsigned short* __restrict__ ud1,
                                              unsigned short* __restrict__ ud2) {
    __shared__ float psx[NN], psy[NN], psz[NN];
    const int bid = blockIdx.x;                 // 8 b * 64 i-chunks
    const int b = bid >> 6, i0 = (bid & 63) * 8;
    const int t = threadIdx.x;
    for (int idx = t; idx < NN; idx += 256) {
        const float* p = pos + ((size_t)b * NN + idx) * 3;
        psx[idx] = p[0]; psy[idx] = p[1]; psz[idx] = p[2];
    }
    __syncthreads();
    const int i = i0 + (t >> 5);
    const float qx = psx[i], qy = psy[i], qz = psz[i];
    const size_t row = ((size_t)b * NN + i) * NN;
    for (int jt = 0; jt < 4; jt++) {
        int j = ((t & 31) + jt * 32) * 4;
        unsigned int o0[2], o1[2], o2[2];
        unsigned short s0[4], s1[4], s2[4];
        #pragma unroll
        for (int u = 0; u < 4; u++) {
            float dx = psx[j + u] - qx, dy = psy[j + u] - qy, dz = psz[j + u] - qz;
            float inv = 1.f / (sqrtf(dx * dx + dy * dy + dz * dz) + 1e-5f);
            s0[u] = f2bf(dx * inv); s1[u] = f2bf(dy * inv); s2[u] = f2bf(dz * inv);
        }
        o0[0] = s0[0] | ((unsigned)s0[1] << 16); o0[1] = s0[2] | ((unsigned)s0[3] << 16);
        o1[0] = s1[0] | ((unsigned)s1[1] << 16); o1[1] = s1[2] | ((unsigned)s1[3] << 16);
        o2[0] = s2[0] | ((unsigned)s2[1] << 16); o2[1] = s2[2] | ((unsigned)s2[3] << 16);
        *(uint2*)&ud0[row + j] = make_uint2(o0[0], o0[1]);
        *(uint2*)&ud1[row + j] = make_uint2(o1[0], o1[1]);
        *(uint2*)&ud2[row + j] = make_uint2(o2[0], o2[1]);
    }
}

// ---------------- K2: bf16 MFMA GEMM  C(4096x1664) = Xb @ WT^T ----------------
// 128x128 tile, BK=64, 4 waves (64x64 each), 16x16x32 MFMA.
// LDS layout [kgrp][row][8 bf16] -> conflict-free ds_read_b128, global_load_lds x16.
__global__ __launch_bounds__(256) void k_gemm_qkv(
        const unsigned short* __restrict__ Xb, const unsigned short* __restrict__ WT,
        const float* __restrict__ bcat,
        unsigned short* __restrict__ qb, unsigned short* __restrict__ kb,
        float* __restrict__ vwb) {
    __shared__ short As[8 * 128 * 8];   // 16 KB
    __shared__ short Bs[8 * 128 * 8];   // 16 KB
    const int t = threadIdx.x;
    const int m0 = blockIdx.x * 128, n0 = blockIdx.y * 128;
    const int w = t >> 6, lane = t & 63, quad = lane >> 4, ln = lane & 15;
    const int wm = (w & 1) * 64, wn = (w >> 1) * 64;

    f32x4 acc[4][4];
    #pragma unroll
    for (int mi = 0; mi < 4; mi++)
        #pragma unroll
        for (int ni = 0; ni < 4; ni++) acc[mi][ni] = (f32x4){0.f, 0.f, 0.f, 0.f};

    for (int k0 = 0; k0 < EDIM; k0 += 64) {
        __syncthreads();
        #pragma unroll
        for (int is = 0; is < 4; is++) {
            int slot = is * 256 + t;
            int g = slot >> 7, m = slot & 127;
            gl2lds16(Xb + (size_t)(m0 + m) * EDIM + k0 + g * 8, &As[(size_t)(is * 256 + w * 64) * 8]);
        }
        #pragma unroll
        for (int is = 0; is < 4; is++) {
            int slot = is * 256 + t;
            int g = slot >> 7, n = slot & 127;
            gl2lds16(WT + (size_t)(n0 + n) * EDIM + k0 + g * 8, &Bs[(size_t)(is * 256 + w * 64) * 8]);
        }
        __syncthreads();
        #pragma unroll
        for (int s = 0; s < 2; s++) {
            short8 af[4], bf[4];
            #pragma unroll
            for (int mi = 0; mi < 4; mi++)
                af[mi] = *(const short8*)&As[(size_t)((s * 4 + quad) * 128 + wm + mi * 16 + ln) * 8];
            #pragma unroll
            for (int ni = 0; ni < 4; ni++)
                bf[ni] = *(const short8*)&Bs[(size_t)((s * 4 + quad) * 128 + wn + ni * 16 + ln) * 8];
            #pragma unroll
            for (int mi = 0; mi < 4; mi++)
                #pragma unroll
                for (int ni = 0; ni < 4; ni++)
                    acc[mi][ni] = __builtin_amdgcn_mfma_f32_16x16x32_bf16(af[mi], bf[ni], acc[mi][ni], 0, 0, 0);
        }
    }

    // epilogue: C row m = quad*4+reg (per 16-tile), col n = ln
    #pragma unroll
    for (int mi = 0; mi < 4; mi++) {
        #pragma unroll
        for (int r = 0; r < 4; r++) {
            int mg = m0 + wm + mi * 16 + quad * 4 + r;
            int b_ = mg >> 9, i_ = mg & (NN - 1);
            #pragma unroll
            for (int ni = 0; ni < 4; ni++) {
                int o = n0 + wn + ni * 16 + ln;
                float val = acc[mi][ni][r] + bcat[o];
                if (o < 768) {
                    int h = o >> 6, d = o & 63;
                    qb[(((size_t)b_ * NH + h) * NN + i_) * HD + d] = f2bf(val * 0.125f);
                } else if (o < 1536) {
                    int o2 = o - 768;
                    int h = o2 >> 6, d = o2 & 63;
                    kb[(((size_t)b_ * NH + h) * NN + i_) * HD + d] = f2bf(val);
                } else if (o < 1572) {
                    int o2 = o - 1536;
                    int h = o2 / 3, c = o2 - (o2 / 3) * 3;
                    vwb[(((size_t)b_ * NH + h) * NN + i_) * 3 + c] = val;
                }
            }
        }
    }
}

// ---------------- K3: fused attention + rotational reduce (MFMA QK^T) ----------------
// block=(b,it,h), 4 waves x 16 i each. S^T tiles: A=K (m=j), B=Q (n=i) -> lane owns one i.
__global__ __launch_bounds__(256) void k_attn(
        const unsigned short* __restrict__ qb, const unsigned short* __restrict__ kb,
        const float* __restrict__ vwb, const float* __restrict__ bias,
        const unsigned short* __restrict__ ud0, const unsigned short* __restrict__ ud1,
        const unsigned short* __restrict__ ud2, float* __restrict__ out) {
    __shared__ short Ks[8 * 64 * 8];    // 8 KB: [dgrp][j][8 bf16]
    __shared__ float ws0[NN], ws1[NN], ws2[NN];

    const int t = threadIdx.x;
    const int bid = blockIdx.x;
    const int h = bid % NH;
    const int it = (bid / NH) & 7;
    const int b = bid / (NH * 8);
    const int i0 = it * 64;
    const int w = t >> 6, lane = t & 63, quad = lane >> 4, ln = lane & 15;
    const size_t bh = (size_t)b * NH + h;

    for (int idx = t; idx < NN * 3; idx += 256) {
        float v = vwb[bh * (NN * 3) + idx];
        int j = idx / 3, c = idx - (idx / 3) * 3;
        if (c == 0) ws0[j] = v; else if (c == 1) ws1[j] = v; else ws2[j] = v;
    }

    const int ig = i0 + w * 16 + ln;
    const unsigned short* qrow = qb + (bh * NN + ig) * HD;
    short8 qf0 = *(const short8*)(qrow + quad * 8);
    short8 qf1 = *(const short8*)(qrow + 32 + quad * 8);
    const float* brow = bias + (bh * NN + ig) * NN;
    const size_t udrow = ((size_t)b * NN + ig) * NN;

    float m_r = -3.0e38f, l_r = 0.f, a0 = 0.f, a1 = 0.f, a2 = 0.f;

    for (int jt = 0; jt < 8; jt++) {
        const int j0 = jt * 64;
        __syncthreads();
        #pragma unroll
        for (int is = 0; is < 2; is++) {
            int slot = is * 256 + t;
            int dg = slot >> 6, j = slot & 63;
            gl2lds16(kb + (bh * NN + j0 + j) * HD + dg * 8, &Ks[(size_t)(is * 256 + w * 64) * 8]);
        }
        __syncthreads();

        f32x4 acc[4];
        #pragma unroll
        for (int sub = 0; sub < 4; sub++) {
            short8 af0 = *(const short8*)&Ks[(size_t)(quad * 64 + sub * 16 + ln) * 8];
            short8 af1 = *(const short8*)&Ks[(size_t)((4 + quad) * 64 + sub * 16 + ln) * 8];
            f32x4 z = {0.f, 0.f, 0.f, 0.f};
            z = __builtin_amdgcn_mfma_f32_16x16x32_bf16(af0, qf0, z, 0, 0, 0);
            z = __builtin_amdgcn_mfma_f32_16x16x32_bf16(af1, qf1, z, 0, 0, 0);
            acc[sub] = z;
        }

        float sv[16];
        #pragma unroll
        for (int sub = 0; sub < 4; sub++) {
            f32x4 bv = *(const f32x4*)(brow + j0 + sub * 16 + quad * 4);
            sv[sub * 4 + 0] = acc[sub][0] + bv[0];
            sv[sub * 4 + 1] = acc[sub][1] + bv[1];
            sv[sub * 4 + 2] = acc[sub][2] + bv[2];
            sv[sub * 4 + 3] = acc[sub][3] + bv[3];
        }
        float lm = sv[0];
        #pragma unroll
        for (int u = 1; u < 16; u++) lm = fmaxf(lm, sv[u]);
        float mn = fmaxf(m_r, lm);
        float alpha = __expf(m_r - mn);
        float lp = 0.f, s0 = 0.f, s1 = 0.f, s2 = 0.f;
        #pragma unroll
        for (int sub = 0; sub < 4; sub++) {
            int j = j0 + sub * 16 + quad * 4;
            f32x4 w0v = *(const f32x4*)&ws0[j];
            f32x4 w1v = *(const f32x4*)&ws1[j];
            f32x4 w2v = *(const f32x4*)&ws2[j];
            union { uint2 u; unsigned short s[4]; } U0, U1, U2;
            U0.u = *(const uint2*)&ud0[udrow + j];
            U1.u = *(const uint2*)&ud1[udrow + j];
            U2.u = *(const uint2*)&ud2[udrow + j];
            #pragma unroll
            for (int r = 0; r < 4; r++) {
                float p = __expf(sv[sub * 4 + r] - mn);
                lp += p;
                s0 = fmaf(p * bf2f(U0.s[r]), w0v[r], s0);
                s1 = fmaf(p * bf2f(U1.s[r]), w1v[r], s1);
                s2 = fmaf(p * bf2f(U2.s[r]), w2v[r], s2);
            }
        }
        l_r = l_r * alpha + lp;
        a0 = a0 * alpha + s0;
        a1 = a1 * alpha + s1;
        a2 = a2 * alpha + s2;
        m_r = mn;
    }

    // merge the 4 quad partials (lanes i, i+16, i+32, i+48)
    #pragma unroll
    for (int off = 16; off <= 32; off <<= 1) {
        float mo = __shfl_xor(m_r, off, 64);
        float lo = __shfl_xor(l_r, off, 64);
        float b0 = __shfl_xor(a0, off, 64);
        float b1 = __shfl_xor(a1, off, 64);
        float b2 = __shfl_xor(a2, off, 64);
        float mn = fmaxf(m_r, mo);
        float e1 = __expf(m_r - mn), e2 = __expf(mo - mn);
        l_r = l_r * e1 + lo * e2;
        a0 = a0 * e1 + b0 * e2;
        a1 = a1 * e1 + b1 * e2;
        a2 = a2 * e1 + b2 * e2;
        m_r = mn;
    }
    if (quad == 0) {
        float inv = 1.f / l_r;
        float* op = out + ((size_t)b * NN + ig) * 3;
        atomicAdd(op + 0, a0 * inv);
        atomicAdd(op + 1, a1 * inv);
        atomicAdd(op + 2, a2 * inv);
    }
}

extern "C" void kernel_launch(void* const* d_in, const int* in_sizes, int n_in,
                              void* d_out, int out_size, void* d_ws, size_t ws_size,
                              hipStream_t stream) {
    const float* query = (const float*)d_in[0];
    const float* bias  = (const float*)d_in[1];
    const float* pos   = (const float*)d_in[2];
    const float* Wq = (const float*)d_in[3];
    const float* bq = (const float*)d_in[4];
    const float* Wk = (const float*)d_in[5];
    const float* bk = (const float*)d_in[6];
    const float* Wv = (const float*)d_in[7];
    const float* bv = (const float*)d_in[8];
    const float* W1 = (const float*)d_in[9];
    const float* b1 = (const float*)d_in[10];
    const float* W2 = (const float*)d_in[11];
    const float* b2 = (const float*)d_in[12];
    const float* W3 = (const float*)d_in[13];
    const float* b3 = (const float*)d_in[14];
    float* out = (float*)d_out;

    char* p = (char*)d_ws;
    float* Wcat = (float*)p;                 p += (size_t)EDIM * NCAT * 4;     // 5.1 MB
    float* bcat = (float*)p;                 p += (size_t)NCAT * 4 + 256;
    unsigned short* WT = (unsigned short*)p; p += (size_t)NCAT * EDIM * 2;     // 2.6 MB
    unsigned short* Xb = (unsigned short*)p; p += (size_t)BSZ * NN * EDIM * 2; // 6.3 MB
    unsigned short* qb = (unsigned short*)p; p += (size_t)BSZ * NH * NN * HD * 2;
    unsigned short* kb = (unsigned short*)p; p += (size_t)BSZ * NH * NN * HD * 2;
    float* vwb = (float*)p;                  p += (size_t)BSZ * NH * NN * 3 * 4;
    unsigned short* ud0 = (unsigned short*)p; p += (size_t)BSZ * NN * NN * 2;
    unsigned short* ud1 = (unsigned short*)p; p += (size_t)BSZ * NN * NN * 2;
    unsigned short* ud2 = (unsigned short*)p; p += (size_t)BSZ * NN * NN * 2;

    k_init_out<<<(BSZ * NN * 3 + 255) / 256, 256, 0, stream>>>(out, b1, b2, b3);
    k_build_wcat<<<(EDIM * NCAT + 255) / 256, 256, 0, stream>>>(Wcat, Wq, Wk, Wv, W1, W2, W3);
    k_build_bcat<<<(NCAT + 255) / 256, 256, 0, stream>>>(bcat, bq, bk, bv, W1, W2, W3);
    dim3 gt(NCAT / 32, EDIM / 32);
    k_transpose_wcat<<<gt, 256, 0, stream>>>(Wcat, WT);
    k_cvt_x<<<(BSZ * NN * 96) / 256, 256, 0, stream>>>(query, Xb);
    k_geom<<<BSZ * 64, 256, 0, stream>>>(pos, ud0, ud1, ud2);
    dim3 g2(32, 13);
    k_gemm_qkv<<<g2, 256, 0, stream>>>(Xb, WT, bcat, qb, kb, vwb);
    k_attn<<<BSZ * 8 * NH, 256, 0, stream>>>(qb, kb, vwb, bias, ud0, ud1, ud2, out);
}